// Round 3
// baseline (329.847 us; speedup 1.0000x reference)
//
#include <hip/hip_runtime.h>
#include <stdint.h>

#define N_Q   16384
#define N_CLS 1024
#define DIM_H 2048
#define NT    (DIM_H / 64)   // 32 k-tiles

typedef __bf16 bf16x8 __attribute__((ext_vector_type(8)));
typedef float  f32x4  __attribute__((ext_vector_type(4)));

__device__ __forceinline__ uint32_t f2bf(float f) {
    uint32_t u = __float_as_uint(f);
    u += 0x7fff + ((u >> 16) & 1);   // RNE
    return u >> 16;
}
// pack two fp32 -> two bf16 (round-to-nearest ties-away): 2 adds + 1 merge
__device__ __forceinline__ uint32_t pk2(float a, float b) {
    uint32_t ua = __float_as_uint(a) + 0x8000u;
    uint32_t ub = __float_as_uint(b) + 0x8000u;
    return (ua >> 16) | (ub & 0xFFFF0000u);
}

// direct-to-LDS 16B staging; HW dest = wave-uniform base + lane*16
__device__ __forceinline__ void load_lds16(const __bf16* g, __bf16* l) {
    __builtin_amdgcn_global_load_lds(
        (const __attribute__((address_space(1))) uint32_t*)g,
        (__attribute__((address_space(3))) uint32_t*)l, 16, 0, 0);
}

// prepass: cls_bf16[c*H+h] = bf16(cls_f32[c*H+h] * M_f32[h])  (12 MB stream)
__global__ void scale_cls_kernel(const float* __restrict__ cls,
                                 const float* __restrict__ M,
                                 uint16_t* __restrict__ o) {
    size_t e = ((size_t)blockIdx.x * 256 + threadIdx.x) * 4;
    float4 c = *(const float4*)(cls + e);
    float4 m = *(const float4*)(M + (e & (DIM_H - 1)));
    uint32_t lo = f2bf(c.x * m.x) | (f2bf(c.y * m.y) << 16);
    uint32_t hi = f2bf(c.z * m.z) | (f2bf(c.w * m.w) << 16);
    *(uint2*)(o + e) = make_uint2(lo, hi);
}

// 128x128 tile, BK=64, 4 waves, 4x4 mfma_f32_16x16x32_bf16 per wave.
// Single-barrier double-buffered pipeline (T3 minimum 2-phase):
//   per iter: issue A(t+1) reg-loads + B(t+1) global_load_lds -> buf[nxt],
//             compute MFMAs on buf[cur] (covers the load latency),
//             cvt+ds_write A(t+1) into As[nxt],
//             ONE __syncthreads (the vmcnt(0)+barrier of the recipe).
// A (queries) read fp32 from global, converted to bf16 in-kernel (no 192 MB
// cvt prepass). B staged bf16 via async global_load_lds (pre-scaled by M).
// LDS XOR-8 swizzle: chunk at (row r, pos p) holds k-chunk p^(r&7).
// Block mapping: xcd=b&7 owns row-panels; 8 col-blocks of one row-panel are
// consecutive t on the SAME XCD -> fp32 A re-reads are L2-local (1 MB/panel).
__global__ __launch_bounds__(256)
void gemm_fused_kernel(const float* __restrict__ Qf,     // (N,H) fp32
                       const uint16_t* __restrict__ Bp,  // (C,H) bf16 pre-scaled
                       float* __restrict__ Out) {        // (N,C) fp32
    __shared__ __align__(16) __bf16 As[2][128 * 64];
    __shared__ __align__(16) __bf16 Bs[2][128 * 64];

    const int tid  = threadIdx.x;
    const int lane = tid & 63;
    const int wave = tid >> 6;

    const int b    = blockIdx.x;            // 0..1023
    const int xcd  = b & 7;
    const int tb   = b >> 3;                // 0..127
    const int row0 = (xcd * 16 + (tb >> 3)) * 128;   // query rows
    const int col0 = (tb & 7) * 128;                 // class cols

    const int wm   = (wave >> 1) * 64;
    const int wn   = (wave & 1) * 64;
    const int frow = lane & 15;
    const int fq   = lane >> 4;

    const __bf16* B = (const __bf16*)Bp;

    // per-lane A chunk geometry (constant over k):
    // LDS chunk c = (i*4+wave)*64 + lane; tile row r = c>>3; global k-chunk
    // g = (c&7)^(r&7)  -> LDS holds the swizzled layout.
    int cidx[4], arow[4], agk[4];
#pragma unroll
    for (int i = 0; i < 4; ++i) {
        const int c = (i * 4 + wave) * 64 + lane;
        cidx[i] = c;
        arow[i] = c >> 3;
        agk[i]  = (c & 7) ^ ((c >> 3) & 7);
    }

    f32x4 acc[4][4] = {};
    float4 ra[4][2];                // in-flight A fp32 (4 chunks x 8 floats)

    // ---- prologue: stage tile 0 into buf 0 ----
#pragma unroll
    for (int i = 0; i < 4; ++i) {
        const float* p = Qf + (size_t)(row0 + arow[i]) * DIM_H + agk[i] * 8;
        ra[i][0] = *(const float4*)p;
        ra[i][1] = *(const float4*)(p + 4);
    }
#pragma unroll
    for (int i = 0; i < 4; ++i) {
        const int chunkbase = (i * 4 + wave) * 64;   // wave-uniform
        const int c = chunkbase + lane;
        const int r = c >> 3;
        const int g = (c & 7) ^ (r & 7);
        load_lds16(B + (size_t)(col0 + r) * DIM_H + g * 8,
                   &Bs[0][chunkbase * 8]);
    }
#pragma unroll
    for (int i = 0; i < 4; ++i) {
        uint4 w = make_uint4(pk2(ra[i][0].x, ra[i][0].y),
                             pk2(ra[i][0].z, ra[i][0].w),
                             pk2(ra[i][1].x, ra[i][1].y),
                             pk2(ra[i][1].z, ra[i][1].w));
        *(uint4*)&As[0][cidx[i] * 8] = w;   // lane-contiguous 16B: conflict-free
    }
    __syncthreads();

#pragma unroll 2
    for (int t = 0; t < NT; ++t) {
        const int cur = t & 1, nxt = cur ^ 1;
        const int kn  = (t + 1) * 64;

        // ---- issue next-tile loads FIRST (compute phase covers latency) ----
        if (t + 1 < NT) {
#pragma unroll
            for (int i = 0; i < 4; ++i) {    // A(t+1): global -> regs
                const float* p = Qf + (size_t)(row0 + arow[i]) * DIM_H
                               + kn + agk[i] * 8;
                ra[i][0] = *(const float4*)p;
                ra[i][1] = *(const float4*)(p + 4);
            }
#pragma unroll
            for (int i = 0; i < 4; ++i) {    // B(t+1): global -> LDS (async)
                const int chunkbase = (i * 4 + wave) * 64;
                const int c = chunkbase + lane;
                const int r = c >> 3;
                const int g = (c & 7) ^ (r & 7);
                load_lds16(B + (size_t)(col0 + r) * DIM_H + kn + g * 8,
                           &Bs[nxt][chunkbase * 8]);
            }
        }

        // ---- compute on buf[cur]: 2 k-steps x 16 MFMA, swizzled reads ----
#pragma unroll
        for (int ks = 0; ks < 2; ++ks) {
            bf16x8 af[4], bfr[4];
#pragma unroll
            for (int tt = 0; tt < 4; ++tt) {
                const int ra2 = wm + tt * 16 + frow;
                const int pa  = ((ks * 4 + fq) ^ (ra2 & 7)) * 8;
                af[tt] = *(const bf16x8*)&As[cur][ra2 * 64 + pa];
                const int rb = wn + tt * 16 + frow;
                const int pb = ((ks * 4 + fq) ^ (rb & 7)) * 8;
                bfr[tt] = *(const bf16x8*)&Bs[cur][rb * 64 + pb];
            }
#pragma unroll
            for (int i = 0; i < 4; ++i)
#pragma unroll
                for (int j = 0; j < 4; ++j)
                    acc[i][j] = __builtin_amdgcn_mfma_f32_16x16x32_bf16(
                        af[i], bfr[j], acc[i][j], 0, 0, 0);
        }

        // ---- A(t+1): cvt + ds_write into As[nxt] (loads now landed) ----
        if (t + 1 < NT) {
#pragma unroll
            for (int i = 0; i < 4; ++i) {
                uint4 w = make_uint4(pk2(ra[i][0].x, ra[i][0].y),
                                     pk2(ra[i][0].z, ra[i][0].w),
                                     pk2(ra[i][1].x, ra[i][1].y),
                                     pk2(ra[i][1].z, ra[i][1].w));
                *(uint4*)&As[nxt][cidx[i] * 8] = w;
            }
        }

        __syncthreads();   // the recipe's vmcnt(0)+barrier: next tile ready
    }

    // ---- epilogue: C/D layout col=lane&15, row=(lane>>4)*4+reg; fp32 out ----
#pragma unroll
    for (int i = 0; i < 4; ++i) {
#pragma unroll
        for (int j = 0; j < 4; ++j) {
            const int row = row0 + wm + i * 16 + fq * 4;
            const int col = col0 + wn + j * 16 + frow;
#pragma unroll
            for (int r = 0; r < 4; ++r)
                Out[(size_t)(row + r) * N_CLS + col] = acc[i][j][r];
        }
    }
}

// correctness fallback (fp32 end-to-end) if workspace is too small
__global__ void naive_kernel(const float* __restrict__ Q,
                             const float* __restrict__ C,
                             const float* __restrict__ M,
                             float* __restrict__ Out) {
    size_t idx = (size_t)blockIdx.x * 256 + threadIdx.x;
    int n = (int)(idx >> 10), c = (int)(idx & (N_CLS - 1));
    float s = 0.f;
    for (int h = 0; h < DIM_H; ++h)
        s += Q[(size_t)n * DIM_H + h] * C[(size_t)c * DIM_H + h] * M[h];
    Out[idx] = s;
}

extern "C" void kernel_launch(void* const* d_in, const int* in_sizes, int n_in,
                              void* d_out, int out_size, void* d_ws, size_t ws_size,
                              hipStream_t stream) {
    const float* cls = (const float*)d_in[0];   // (C,H)  = 2,097,152
    const float* q   = (const float*)d_in[1];   // (N,H)  = 33,554,432
    const float* M   = (const float*)d_in[2];   // (H,1)  = 2,048
    for (int i = 0; i < n_in; ++i) {
        if      (in_sizes[i] == N_CLS * DIM_H) cls = (const float*)d_in[i];
        else if (in_sizes[i] == N_Q * DIM_H)   q   = (const float*)d_in[i];
        else if (in_sizes[i] == DIM_H)         M   = (const float*)d_in[i];
    }
    float* out = (float*)d_out;

    const size_t cls_bytes = (size_t)N_CLS * DIM_H * sizeof(uint16_t);  // 4 MB
    if (ws_size >= cls_bytes) {
        uint16_t* cls_bf = (uint16_t*)d_ws;
        scale_cls_kernel<<<(N_CLS * DIM_H) / (256 * 4), 256, 0, stream>>>(cls, M, cls_bf);
        gemm_fused_kernel<<<(N_Q / 128) * (N_CLS / 128), 256, 0, stream>>>(q, cls_bf, out);
    } else {
        naive_kernel<<<(unsigned)(((size_t)N_Q * N_CLS) / 256), 256, 0, stream>>>(q, cls, M, out);
    }
}

// Round 4
// 284.085 us; speedup vs baseline: 1.1611x; 1.1611x over previous
//
#include <hip/hip_runtime.h>
#include <stdint.h>

#define N_Q   16384
#define N_CLS 1024
#define DIM_H 2048
#define NT    (DIM_H / 64)                    // 32 k-tiles
#define QBLK  ((N_Q * DIM_H) / (256 * 8))     // 16384 blocks for Q cvt
#define CBLK  ((N_CLS * DIM_H) / (256 * 8))   // 1024 blocks for cls cvt

typedef __bf16 bf16x8 __attribute__((ext_vector_type(8)));
typedef float  f32x4  __attribute__((ext_vector_type(4)));

// pack two fp32 -> two bf16 (round-to-nearest ties-away): 2 adds + 1 merge
__device__ __forceinline__ uint32_t pk2(float a, float b) {
    uint32_t ua = __float_as_uint(a) + 0x8000u;
    uint32_t ub = __float_as_uint(b) + 0x8000u;
    return (ua >> 16) | (ub & 0xFFFF0000u);
}

// direct-to-LDS 16B staging; HW dest = wave-uniform base + lane*16
__device__ __forceinline__ void load_lds16(const __bf16* g, __bf16* l) {
    __builtin_amdgcn_global_load_lds(
        (const __attribute__((address_space(1))) uint32_t*)g,
        (__attribute__((address_space(3))) uint32_t*)l, 16, 0, 0);
}

// single prepass: Q fp32->bf16 (blocks 0..QBLK-1), cls fp32*M->bf16 (rest)
__global__ void prep_kernel(const float* __restrict__ q,
                            const float* __restrict__ cls,
                            const float* __restrict__ M,
                            uint16_t* __restrict__ qo,
                            uint16_t* __restrict__ co) {
    const int bid = blockIdx.x;
    if (bid < QBLK) {
        size_t e = ((size_t)bid * 256 + threadIdx.x) * 8;
        float4 a = *(const float4*)(q + e);
        float4 b = *(const float4*)(q + e + 4);
        *(uint4*)(qo + e) = make_uint4(pk2(a.x, a.y), pk2(a.z, a.w),
                                       pk2(b.x, b.y), pk2(b.z, b.w));
    } else {
        size_t e = ((size_t)(bid - QBLK) * 256 + threadIdx.x) * 8;
        float4 c0 = *(const float4*)(cls + e);
        float4 c1 = *(const float4*)(cls + e + 4);
        const float* mp = M + (e & (DIM_H - 1));
        float4 m0 = *(const float4*)mp;
        float4 m1 = *(const float4*)(mp + 4);
        *(uint4*)(co + e) = make_uint4(pk2(c0.x * m0.x, c0.y * m0.y),
                                       pk2(c0.z * m0.z, c0.w * m0.w),
                                       pk2(c1.x * m1.x, c1.y * m1.y),
                                       pk2(c1.z * m1.z, c1.w * m1.w));
    }
}

// 256x256 tile, BK=64, 8 waves (2M x 4N), per-wave 128x64 output.
// Grid = 64 x 4 = 256 blocks = exactly 1 block/CU (8 waves, 128KB LDS).
// Counted-vmcnt double-buffer (T3+T4): per K-tile iteration:
//   issue tile t+1's 8 global_load_lds into slot s^1   (stay in flight)
//   s_waitcnt vmcnt(8)   <- tile t's 8 loads (the only older ones) landed
//   s_barrier            <- all waves agree slot s holds tile t
//   64 MFMA/wave on slot s (2 ks-steps; ~2500 cyc cover for t+1's loads)
//   s_barrier            <- all reads of slot s done; next iter may overwrite
// Raw s_barrier (NOT __syncthreads) so the compiler does not drain vmcnt(0).
// LDS XOR-8 chunk swizzle (proven, 0 conflicts): chunk at (row r, pos p)
// holds global k-chunk p^(r&7); fragment read pos = (ks*4+fq)^(frow&7).
// Block mapping: xcd=b&7 owns 8 row-panels; col changes every 8 blocks ->
// B col-panel (1MB) L2-resident per XCD.
__global__ __launch_bounds__(512, 2)
void gemm_kernel(const uint16_t* __restrict__ Qp,   // (N,H) bf16
                 const uint16_t* __restrict__ Bp,   // (C,H) bf16 pre-scaled
                 float* __restrict__ Out) {         // (N,C) fp32
    __shared__ __align__(16) __bf16 As[2][256 * 64];
    __shared__ __align__(16) __bf16 Bs[2][256 * 64];

    const int tid  = threadIdx.x;
    const int lane = tid & 63;
    const int wave = tid >> 6;

    const int b    = blockIdx.x;            // 0..255
    const int xcd  = b & 7;
    const int t0   = b >> 3;                // 0..31
    const int row0 = (xcd * 8 + (t0 & 7)) * 256;    // query rows (64 panels)
    const int col0 = (t0 >> 3) * 256;               // class cols (4 panels)

    const int wm   = (wave >> 2) * 128;     // 2 waves in M
    const int wn   = (wave & 3) * 64;       // 4 waves in N
    const int frow = lane & 15;
    const int fq   = lane >> 4;

    const __bf16* Q = (const __bf16*)Qp;
    const __bf16* B = (const __bf16*)Bp;

    f32x4 acc[8][4] = {};

    // stage K-tile kt (A: 256x64, B: 256x64) into slot s: 8 gloads/thread.
    // chunk c = i*512 + tid; r = c>>3 (tile row), g = (c&7)^(r&7) (k-chunk).
    // LDS dest chunkbase = i*512 + wave*64 is wave-uniform; lanes fill +lane.
    auto stage = [&](int kt, int s) {
#pragma unroll
        for (int i = 0; i < 4; ++i) {
            const int cb = i * 512 + wave * 64;
            const int c  = cb + lane;
            const int r  = c >> 3;
            const int g  = (c & 7) ^ (r & 7);
            load_lds16(Q + (size_t)(row0 + r) * DIM_H + kt * 64 + g * 8,
                       &As[s][cb * 8]);
            load_lds16(B + (size_t)(col0 + r) * DIM_H + kt * 64 + g * 8,
                       &Bs[s][cb * 8]);
        }
    };

    stage(0, 0);   // prologue: tile 0 -> slot 0 (8 loads in flight)

    for (int t = 0; t < NT; ++t) {
        const int s = t & 1;

        if (t + 1 < NT) {
            stage(t + 1, s ^ 1);                     // 8 more loads in flight
            asm volatile("s_waitcnt vmcnt(8)" ::: "memory");  // tile t landed
        } else {
            asm volatile("s_waitcnt vmcnt(0)" ::: "memory");
        }
        __builtin_amdgcn_s_barrier();                // slot s ready (all waves)

        // ---- compute: 2 ks-steps x 32 MFMA, swizzled fragment reads ----
#pragma unroll
        for (int ks = 0; ks < 2; ++ks) {
            const int x = ((ks * 4 + fq) ^ (frow & 7)) * 8;
            bf16x8 af[8], bfr[4];
#pragma unroll
            for (int tt = 0; tt < 8; ++tt)
                af[tt] = *(const bf16x8*)&As[s][(wm + tt * 16 + frow) * 64 + x];
#pragma unroll
            for (int u = 0; u < 4; ++u)
                bfr[u] = *(const bf16x8*)&Bs[s][(wn + u * 16 + frow) * 64 + x];
#pragma unroll
            for (int tt = 0; tt < 8; ++tt)
#pragma unroll
                for (int u = 0; u < 4; ++u)
                    acc[tt][u] = __builtin_amdgcn_mfma_f32_16x16x32_bf16(
                        af[tt], bfr[u], acc[tt][u], 0, 0, 0);
        }

        if (t + 1 < NT)
            __builtin_amdgcn_s_barrier();            // reads done; slot s^1
    }                                                //  overwrite safe next it

    // ---- epilogue: C/D layout col=lane&15, row=(lane>>4)*4+reg; fp32 out ----
#pragma unroll
    for (int tt = 0; tt < 8; ++tt) {
#pragma unroll
        for (int u = 0; u < 4; ++u) {
            const int row = row0 + wm + tt * 16 + fq * 4;
            const int col = col0 + wn + u * 16 + frow;
#pragma unroll
            for (int r = 0; r < 4; ++r)
                Out[(size_t)(row + r) * N_CLS + col] = acc[tt][u][r];
        }
    }
}

// correctness fallback (fp32 end-to-end) if workspace is too small
__global__ void naive_kernel(const float* __restrict__ Q,
                             const float* __restrict__ C,
                             const float* __restrict__ M,
                             float* __restrict__ Out) {
    size_t idx = (size_t)blockIdx.x * 256 + threadIdx.x;
    int n = (int)(idx >> 10), c = (int)(idx & (N_CLS - 1));
    float s = 0.f;
    for (int h = 0; h < DIM_H; ++h)
        s += Q[(size_t)n * DIM_H + h] * C[(size_t)c * DIM_H + h] * M[h];
    Out[idx] = s;
}

extern "C" void kernel_launch(void* const* d_in, const int* in_sizes, int n_in,
                              void* d_out, int out_size, void* d_ws, size_t ws_size,
                              hipStream_t stream) {
    const float* cls = (const float*)d_in[0];   // (C,H)
    const float* q   = (const float*)d_in[1];   // (N,H)
    const float* M   = (const float*)d_in[2];   // (H,1)
    for (int i = 0; i < n_in; ++i) {
        if      (in_sizes[i] == N_CLS * DIM_H) cls = (const float*)d_in[i];
        else if (in_sizes[i] == N_Q * DIM_H)   q   = (const float*)d_in[i];
        else if (in_sizes[i] == DIM_H)         M   = (const float*)d_in[i];
    }
    float* out = (float*)d_out;

    const size_t cls_bytes = (size_t)N_CLS * DIM_H * sizeof(uint16_t);  //  4 MB
    const size_t q_bytes   = (size_t)N_Q * DIM_H * sizeof(uint16_t);    // 67 MB
    if (ws_size >= cls_bytes + q_bytes) {
        uint16_t* cls_bf = (uint16_t*)d_ws;
        uint16_t* q_bf   = (uint16_t*)((char*)d_ws + cls_bytes);
        prep_kernel<<<QBLK + CBLK, 256, 0, stream>>>(q, cls, M, q_bf, cls_bf);
        gemm_kernel<<<(N_Q / 256) * (N_CLS / 256), 512, 0, stream>>>(q_bf, cls_bf, out);
    } else {
        naive_kernel<<<(unsigned)(((size_t)N_Q * N_CLS) / 256), 256, 0, stream>>>(q, cls, M, out);
    }
}